// Round 10
// baseline (75.724 us; speedup 1.0000x reference)
//
#include <hip/hip_runtime.h>

// ROIAlign, MI355X. feat (4,256,128,128) f32, rois (1024,5) f32,
// out (1024,256,7,7) f32. scale=0.25, sampling=2.
// Pipeline: repack NCHW f32 -> NHWC bf16 in d_ws; gather with 16-lane slot
// per bin, lane owns 8 channels. Round-8 structure (grid 2K, 256thr, LDS-
// staged coalesced writeout) + within-bin 16-load hoist: all corner loads
// issued back-to-back (latency overlap), validity as 0/1 weight multiplier
// (no divergent branches). Accumulation order bitwise-identical to round 8.

typedef unsigned short u16;
typedef unsigned int u32;

#define FW 128
#define FHW 16384
#define NC 256
#define NB 4
#define HALF_C 128
#define OUT_PER_HALF 6272   // HALF_C * 49
#define TILE_P 129          // odd row stride -> conflict-free transposed reads
#define KROIS 1024

static __device__ __forceinline__ float bfhi(u32 v) {
  return __uint_as_float(v & 0xFFFF0000u);
}
static __device__ __forceinline__ float bflo(u32 v) {
  return __uint_as_float(v << 16);
}

// ---- Kernel 1: transpose [B][C][HW] f32 -> [B][HW][C] bf16 (proven) ----
__global__ __launch_bounds__(256) void repack_kernel(const float* __restrict__ feat,
                                                     u16* __restrict__ ws) {
  __shared__ u16 tile[64][66];
  int hw0 = blockIdx.x * 64;
  int c0  = blockIdx.y * 64;
  int b   = blockIdx.z;
  const float* src = feat + (size_t)b * NC * FHW;
  int t   = threadIdx.x;
  int lhw = t & 63;
  int lc  = t >> 6;
#pragma unroll
  for (int i = 0; i < 16; ++i) {
    int c = lc + i * 4;
    float v = src[(size_t)(c0 + c) * FHW + hw0 + lhw];
    u32 u = __float_as_uint(v);
    u += 0x7FFFu + ((u >> 16) & 1u);  // RNE f32->bf16
    tile[lhw][c] = (u16)(u >> 16);
  }
  __syncthreads();
  u16* dst = ws + (size_t)b * FHW * NC;
  int c2 = (t & 31) * 2;
  int r0 = t >> 5;
#pragma unroll
  for (int i = 0; i < 8; ++i) {
    int r = r0 + i * 8;
    u32 val = *(const u32*)&tile[r][c2];
    *(u32*)&dst[(size_t)(hw0 + r) * NC + c0 + c2] = val;
  }
}

// ---- Kernel 2: gather. grid 2*K (1D), block 256 (16 slots x 16 lanes) ----
__global__ __launch_bounds__(256) void gather_kernel(const u16* __restrict__ ws,
                                                     const float* __restrict__ rois,
                                                     float* __restrict__ out) {
  __shared__ float tile[49][TILE_P];  // 25.3 KB
  int bid    = blockIdx.x;
  int k      = bid >> 1;
  int half   = bid & 1;
  int t      = threadIdx.x;
  int slot   = t >> 4;    // 0..15
  int lane16 = t & 15;
  int cl     = lane16 * 8;              // channel offset within half

  int   b  = (int)rois[k * 5 + 0];
  float x1 = rois[k * 5 + 1] * 0.25f;
  float y1 = rois[k * 5 + 2] * 0.25f;
  float x2 = rois[k * 5 + 3] * 0.25f;
  float y2 = rois[k * 5 + 4] * 0.25f;
  float bw = fmaxf(x2 - x1, 1.0f) * (1.0f / 7.0f);
  float bh = fmaxf(y2 - y1, 1.0f) * (1.0f / 7.0f);

  const u16* plane = ws + (size_t)b * FHW * NC + half * HALF_C + cl;
  const int s0 = slot ? 3 * slot + 1 : 0;
  const int nb = slot ? 3 : 4;

  float acc[4][8];
#pragma unroll
  for (int i = 0; i < 4; ++i)
#pragma unroll
    for (int ch = 0; ch < 8; ++ch) acc[i][ch] = 0.0f;

#pragma unroll
  for (int i = 0; i < 4; ++i) {
    if (i < nb) {  // uniform within 16-lane slot; acc indices stay static
      int s  = s0 + i;
      int ph = s / 7, pw = s - ph * 7;

      int xl[2], xh[2]; float fx[2]; bool vx[2];
#pragma unroll
      for (int ix = 0; ix < 2; ++ix) {
        float xx = x1 + bw * ((float)pw + (ix ? 0.75f : 0.25f));
        vx[ix] = (xx >= -1.0f) && (xx <= 128.0f);
        float xc = fmaxf(xx, 0.0f);
        int l = min((int)xc, 127);
        xl[ix] = l; xh[ix] = min(l + 1, 127); fx[ix] = xc - (float)l;
      }
      int yl[2], yh[2]; float fy[2]; bool vy[2];
#pragma unroll
      for (int iy = 0; iy < 2; ++iy) {
        float yy = y1 + bh * ((float)ph + (iy ? 0.75f : 0.25f));
        vy[iy] = (yy >= -1.0f) && (yy <= 128.0f);
        float yc = fmaxf(yy, 0.0f);
        int l = min((int)yc, 127);
        yl[iy] = l; yh[iy] = min(l + 1, 127); fy[iy] = yc - (float)l;
      }

      // --- hoist: all 16 corner loads issued unconditionally (clamped
      // addresses are always in-bounds), latencies overlap ---
      uint4 v[2][2][4];
#pragma unroll
      for (int iy = 0; iy < 2; ++iy) {
#pragma unroll
        for (int ix = 0; ix < 2; ++ix) {
          v[iy][ix][0] = *(const uint4*)(plane + (yl[iy] * FW + xl[ix]) * NC);
          v[iy][ix][1] = *(const uint4*)(plane + (yl[iy] * FW + xh[ix]) * NC);
          v[iy][ix][2] = *(const uint4*)(plane + (yh[iy] * FW + xl[ix]) * NC);
          v[iy][ix][3] = *(const uint4*)(plane + (yh[iy] * FW + xh[ix]) * NC);
        }
      }

      // --- weights (validity as 0/1 multiplier) + FMAs; same per-sample
      // accumulation order as round 8 -> bitwise-identical results ---
#pragma unroll
      for (int iy = 0; iy < 2; ++iy) {
#pragma unroll
        for (int ix = 0; ix < 2; ++ix) {
          float m   = (vy[iy] && vx[ix]) ? 1.0f : 0.0f;
          float ly_ = fy[iy], hy = 1.0f - ly_;
          float lx_ = fx[ix], hx = 1.0f - lx_;
          float w00 = m * hy * hx, w01 = m * hy * lx_;
          float w10 = m * ly_ * hx, w11 = m * ly_ * lx_;
          const uint4 v00 = v[iy][ix][0], v01 = v[iy][ix][1];
          const uint4 v10 = v[iy][ix][2], v11 = v[iy][ix][3];
          acc[i][0] += w00 * bflo(v00.x) + w01 * bflo(v01.x) + w10 * bflo(v10.x) + w11 * bflo(v11.x);
          acc[i][1] += w00 * bfhi(v00.x) + w01 * bfhi(v01.x) + w10 * bfhi(v10.x) + w11 * bfhi(v11.x);
          acc[i][2] += w00 * bflo(v00.y) + w01 * bflo(v01.y) + w10 * bflo(v10.y) + w11 * bflo(v11.y);
          acc[i][3] += w00 * bfhi(v00.y) + w01 * bfhi(v01.y) + w10 * bfhi(v10.y) + w11 * bfhi(v11.y);
          acc[i][4] += w00 * bflo(v00.z) + w01 * bflo(v01.z) + w10 * bflo(v10.z) + w11 * bflo(v11.z);
          acc[i][5] += w00 * bfhi(v00.z) + w01 * bfhi(v01.z) + w10 * bfhi(v10.z) + w11 * bfhi(v11.z);
          acc[i][6] += w00 * bflo(v00.w) + w01 * bflo(v01.w) + w10 * bflo(v10.w) + w11 * bflo(v11.w);
          acc[i][7] += w00 * bfhi(v00.w) + w01 * bfhi(v01.w) + w10 * bfhi(v10.w) + w11 * bfhi(v11.w);
        }
      }
    }
  }

  // Stage: tile[s][c_local]; every cell written exactly once.
#pragma unroll
  for (int i = 0; i < 4; ++i) {
    if (i < nb) {
      int s = s0 + i;
#pragma unroll
      for (int ch = 0; ch < 8; ++ch) tile[s][cl + ch] = acc[i][ch] * 0.25f;
    }
  }
  __syncthreads();

  // Coalesced writeout.
  float* o = out + (size_t)k * (NC * 49) + half * OUT_PER_HALF;
#pragma unroll
  for (int i = 0; i < 25; ++i) {
    int f = t + i * 256;
    if (f < OUT_PER_HALF) {
      int c = f / 49;  // compiler magic-mul
      int s = f - c * 49;
      o[f] = tile[s][c];
    }
  }
}

// ---- Fallback: direct NCHW kernel (round-2 proven) ----
__global__ __launch_bounds__(256) void ROIAlign_direct(const float* __restrict__ feat,
                                                       const float* __restrict__ rois,
                                                       float* __restrict__ out, int n) {
  int o = blockIdx.x * 256 + threadIdx.x;
  if (o >= n) return;
  int pw = o % 7;
  int t1 = o / 7;
  int ph = t1 % 7;
  int t2 = t1 / 7;
  int c = t2 & 255;
  int k = t2 >> 8;

  int rb = k * 5;
  int b = (int)rois[rb + 0];
  float x1 = rois[rb + 1] * 0.25f, y1 = rois[rb + 2] * 0.25f;
  float x2 = rois[rb + 3] * 0.25f, y2 = rois[rb + 4] * 0.25f;
  float bw = fmaxf(x2 - x1, 1.0f) / 7.0f;
  float bh = fmaxf(y2 - y1, 1.0f) / 7.0f;

  int xl[2], xh[2]; float fx[2]; bool vx[2];
#pragma unroll
  for (int ix = 0; ix < 2; ++ix) {
    float xx = x1 + bw * ((float)pw + (ix ? 0.75f : 0.25f));
    vx[ix] = (xx >= -1.0f) && (xx <= 128.0f);
    float xc = fmaxf(xx, 0.0f);
    int l = min((int)xc, 127);
    xl[ix] = l; xh[ix] = min(l + 1, 127); fx[ix] = xc - (float)l;
  }
  int yl[2], yh[2]; float fy[2]; bool vy[2];
#pragma unroll
  for (int iy = 0; iy < 2; ++iy) {
    float yy = y1 + bh * ((float)ph + (iy ? 0.75f : 0.25f));
    vy[iy] = (yy >= -1.0f) && (yy <= 128.0f);
    float yc = fmaxf(yy, 0.0f);
    int l = min((int)yc, 127);
    yl[iy] = l; yh[iy] = min(l + 1, 127); fy[iy] = yc - (float)l;
  }
  const int plane = (b * 256 + c) << 14;
  float acc = 0.0f;
#pragma unroll
  for (int iy = 0; iy < 2; ++iy) {
    int ro0 = plane + (yl[iy] << 7);
    int ro1 = plane + (yh[iy] << 7);
#pragma unroll
    for (int ix = 0; ix < 2; ++ix) {
      if (vy[iy] && vx[ix]) {
        float ly_ = fy[iy], hy = 1.0f - ly_;
        float lx_ = fx[ix], hx = 1.0f - lx_;
        acc += hy * (hx * feat[ro0 + xl[ix]] + lx_ * feat[ro0 + xh[ix]]) +
               ly_ * (hx * feat[ro1 + xl[ix]] + lx_ * feat[ro1 + xh[ix]]);
      }
    }
  }
  out[o] = acc * 0.25f;
}

extern "C" void kernel_launch(void* const* d_in, const int* in_sizes, int n_in,
                              void* d_out, int out_size, void* d_ws, size_t ws_size,
                              hipStream_t stream) {
  const float* feat = (const float*)d_in[0];
  const float* rois = (const float*)d_in[1];
  float* out = (float*)d_out;
  int n = out_size;
  size_t need = (size_t)NB * FHW * NC * sizeof(u16);  // 33.55 MB
  if (ws_size >= need) {
    repack_kernel<<<dim3(FHW / 64, NC / 64, NB), 256, 0, stream>>>(feat, (u16*)d_ws);
    gather_kernel<<<dim3(2 * KROIS), 256, 0, stream>>>((const u16*)d_ws, rois, out);
  } else {
    ROIAlign_direct<<<(n + 255) / 256, 256, 0, stream>>>(feat, rois, out, n);
  }
}

// Round 11
// 63.708 us; speedup vs baseline: 1.1886x; 1.1886x over previous
//
#include <hip/hip_runtime.h>

// ROIAlign, MI355X. feat (4,256,128,128) f32, rois (1024,5) f32,
// out (1024,256,7,7) f32. scale=0.25, sampling=2.
// Pipeline: repack NCHW f32 -> NHWC bf16 in d_ws; gather (round-8 proven
// body: 16-lane slot per bin, lane owns 8 channels, uint4 corner loads,
// LDS-staged coalesced writeout) run as a fully co-resident balanced grid:
// 1024 blocks (4/CU, under the 6/CU LDS cap), each does exactly 2
// roi-halves -> no ramp/tail imbalance.

typedef unsigned short u16;
typedef unsigned int u32;

#define FW 128
#define FHW 16384
#define NC 256
#define NB 4
#define HALF_C 128
#define OUT_PER_HALF 6272   // HALF_C * 49
#define TILE_P 129          // odd row stride -> conflict-free transposed reads
#define KROIS 1024
#define GATHER_BLOCKS 1024
#define ITEMS 2             // roi-halves per block

static __device__ __forceinline__ float bfhi(u32 v) {
  return __uint_as_float(v & 0xFFFF0000u);
}
static __device__ __forceinline__ float bflo(u32 v) {
  return __uint_as_float(v << 16);
}

// ---- Kernel 1: transpose [B][C][HW] f32 -> [B][HW][C] bf16 (proven) ----
__global__ __launch_bounds__(256) void repack_kernel(const float* __restrict__ feat,
                                                     u16* __restrict__ ws) {
  __shared__ u16 tile[64][66];
  int hw0 = blockIdx.x * 64;
  int c0  = blockIdx.y * 64;
  int b   = blockIdx.z;
  const float* src = feat + (size_t)b * NC * FHW;
  int t   = threadIdx.x;
  int lhw = t & 63;
  int lc  = t >> 6;
#pragma unroll
  for (int i = 0; i < 16; ++i) {
    int c = lc + i * 4;
    float v = src[(size_t)(c0 + c) * FHW + hw0 + lhw];
    u32 u = __float_as_uint(v);
    u += 0x7FFFu + ((u >> 16) & 1u);  // RNE f32->bf16
    tile[lhw][c] = (u16)(u >> 16);
  }
  __syncthreads();
  u16* dst = ws + (size_t)b * FHW * NC;
  int c2 = (t & 31) * 2;
  int r0 = t >> 5;
#pragma unroll
  for (int i = 0; i < 8; ++i) {
    int r = r0 + i * 8;
    u32 val = *(const u32*)&tile[r][c2];
    *(u32*)&dst[(size_t)(hw0 + r) * NC + c0 + c2] = val;
  }
}

// ---- Kernel 2: gather. grid 1024, block 256 (16 slots x 16 lanes) ----
// Block handles roi-halves lin = bid and bid+1024 (balanced, co-resident).
// Per item: k = lin>>1, half = lin&1. Slot t>>4 owns bins (slot 0 -> s 0..3,
// slot j>0 -> 3j+1..3j+3); lane t&15 owns 8 channels of the half.
__global__ __launch_bounds__(256) void gather_kernel(const u16* __restrict__ ws,
                                                     const float* __restrict__ rois,
                                                     float* __restrict__ out) {
  __shared__ float tile[49][TILE_P];  // 25.3 KB
  int bid    = blockIdx.x;
  int t      = threadIdx.x;
  int slot   = t >> 4;    // 0..15
  int lane16 = t & 15;
  int cl     = lane16 * 8;              // channel offset within half
  const int s0 = slot ? 3 * slot + 1 : 0;
  const int nb = slot ? 3 : 4;

  for (int rep = 0; rep < ITEMS; ++rep) {
    int lin  = bid + rep * GATHER_BLOCKS;
    int k    = lin >> 1;
    int half = lin & 1;

    int   b  = (int)rois[k * 5 + 0];
    float x1 = rois[k * 5 + 1] * 0.25f;
    float y1 = rois[k * 5 + 2] * 0.25f;
    float x2 = rois[k * 5 + 3] * 0.25f;
    float y2 = rois[k * 5 + 4] * 0.25f;
    float bw = fmaxf(x2 - x1, 1.0f) * (1.0f / 7.0f);
    float bh = fmaxf(y2 - y1, 1.0f) * (1.0f / 7.0f);

    const u16* plane = ws + (size_t)b * FHW * NC + half * HALF_C + cl;

    float acc[4][8];
#pragma unroll
    for (int i = 0; i < 4; ++i)
#pragma unroll
      for (int ch = 0; ch < 8; ++ch) acc[i][ch] = 0.0f;

#pragma unroll
    for (int i = 0; i < 4; ++i) {
      if (i < nb) {  // uniform within 16-lane slot; acc indices stay static
        int s  = s0 + i;
        int ph = s / 7, pw = s - ph * 7;

        int xl[2], xh[2]; float fx[2]; bool vx[2];
#pragma unroll
        for (int ix = 0; ix < 2; ++ix) {
          float xx = x1 + bw * ((float)pw + (ix ? 0.75f : 0.25f));
          vx[ix] = (xx >= -1.0f) && (xx <= 128.0f);
          float xc = fmaxf(xx, 0.0f);
          int l = min((int)xc, 127);
          xl[ix] = l; xh[ix] = min(l + 1, 127); fx[ix] = xc - (float)l;
        }
        int yl[2], yh[2]; float fy[2]; bool vy[2];
#pragma unroll
        for (int iy = 0; iy < 2; ++iy) {
          float yy = y1 + bh * ((float)ph + (iy ? 0.75f : 0.25f));
          vy[iy] = (yy >= -1.0f) && (yy <= 128.0f);
          float yc = fmaxf(yy, 0.0f);
          int l = min((int)yc, 127);
          yl[iy] = l; yh[iy] = min(l + 1, 127); fy[iy] = yc - (float)l;
        }

#pragma unroll
        for (int iy = 0; iy < 2; ++iy) {
#pragma unroll
          for (int ix = 0; ix < 2; ++ix) {
            if (vy[iy] && vx[ix]) {
              float ly_ = fy[iy], hy = 1.0f - ly_;
              float lx_ = fx[ix], hx = 1.0f - lx_;
              float w00 = hy * hx, w01 = hy * lx_, w10 = ly_ * hx, w11 = ly_ * lx_;
              const uint4 v00 = *(const uint4*)(plane + (yl[iy] * FW + xl[ix]) * NC);
              const uint4 v01 = *(const uint4*)(plane + (yl[iy] * FW + xh[ix]) * NC);
              const uint4 v10 = *(const uint4*)(plane + (yh[iy] * FW + xl[ix]) * NC);
              const uint4 v11 = *(const uint4*)(plane + (yh[iy] * FW + xh[ix]) * NC);
              acc[i][0] += w00 * bflo(v00.x) + w01 * bflo(v01.x) + w10 * bflo(v10.x) + w11 * bflo(v11.x);
              acc[i][1] += w00 * bfhi(v00.x) + w01 * bfhi(v01.x) + w10 * bfhi(v10.x) + w11 * bfhi(v11.x);
              acc[i][2] += w00 * bflo(v00.y) + w01 * bflo(v01.y) + w10 * bflo(v10.y) + w11 * bflo(v11.y);
              acc[i][3] += w00 * bfhi(v00.y) + w01 * bfhi(v01.y) + w10 * bfhi(v10.y) + w11 * bfhi(v11.y);
              acc[i][4] += w00 * bflo(v00.z) + w01 * bflo(v01.z) + w10 * bflo(v10.z) + w11 * bflo(v11.z);
              acc[i][5] += w00 * bfhi(v00.z) + w01 * bfhi(v01.z) + w10 * bfhi(v10.z) + w11 * bfhi(v11.z);
              acc[i][6] += w00 * bflo(v00.w) + w01 * bflo(v01.w) + w10 * bflo(v10.w) + w11 * bflo(v11.w);
              acc[i][7] += w00 * bfhi(v00.w) + w01 * bfhi(v01.w) + w10 * bfhi(v10.w) + w11 * bfhi(v11.w);
            }
          }
        }
      }
    }

    // Stage: tile[s][c_local]; every cell written exactly once.
#pragma unroll
    for (int i = 0; i < 4; ++i) {
      if (i < nb) {
        int s = s0 + i;
#pragma unroll
        for (int ch = 0; ch < 8; ++ch) tile[s][cl + ch] = acc[i][ch] * 0.25f;
      }
    }
    __syncthreads();

    // Coalesced writeout.
    float* o = out + (size_t)k * (NC * 49) + half * OUT_PER_HALF;
#pragma unroll
    for (int i = 0; i < 25; ++i) {
      int f = t + i * 256;
      if (f < OUT_PER_HALF) {
        int c = f / 49;  // compiler magic-mul
        int s = f - c * 49;
        o[f] = tile[s][c];
      }
    }
    __syncthreads();  // recycle tile before next item's staging
  }
}

// ---- Fallback: direct NCHW kernel (round-2 proven) ----
__global__ __launch_bounds__(256) void ROIAlign_direct(const float* __restrict__ feat,
                                                       const float* __restrict__ rois,
                                                       float* __restrict__ out, int n) {
  int o = blockIdx.x * 256 + threadIdx.x;
  if (o >= n) return;
  int pw = o % 7;
  int t1 = o / 7;
  int ph = t1 % 7;
  int t2 = t1 / 7;
  int c = t2 & 255;
  int k = t2 >> 8;

  int rb = k * 5;
  int b = (int)rois[rb + 0];
  float x1 = rois[rb + 1] * 0.25f, y1 = rois[rb + 2] * 0.25f;
  float x2 = rois[rb + 3] * 0.25f, y2 = rois[rb + 4] * 0.25f;
  float bw = fmaxf(x2 - x1, 1.0f) / 7.0f;
  float bh = fmaxf(y2 - y1, 1.0f) / 7.0f;

  int xl[2], xh[2]; float fx[2]; bool vx[2];
#pragma unroll
  for (int ix = 0; ix < 2; ++ix) {
    float xx = x1 + bw * ((float)pw + (ix ? 0.75f : 0.25f));
    vx[ix] = (xx >= -1.0f) && (xx <= 128.0f);
    float xc = fmaxf(xx, 0.0f);
    int l = min((int)xc, 127);
    xl[ix] = l; xh[ix] = min(l + 1, 127); fx[ix] = xc - (float)l;
  }
  int yl[2], yh[2]; float fy[2]; bool vy[2];
#pragma unroll
  for (int iy = 0; iy < 2; ++iy) {
    float yy = y1 + bh * ((float)ph + (iy ? 0.75f : 0.25f));
    vy[iy] = (yy >= -1.0f) && (yy <= 128.0f);
    float yc = fmaxf(yy, 0.0f);
    int l = min((int)yc, 127);
    yl[iy] = l; yh[iy] = min(l + 1, 127); fy[iy] = yc - (float)l;
  }
  const int plane = (b * 256 + c) << 14;
  float acc = 0.0f;
#pragma unroll
  for (int iy = 0; iy < 2; ++iy) {
    int ro0 = plane + (yl[iy] << 7);
    int ro1 = plane + (yh[iy] << 7);
#pragma unroll
    for (int ix = 0; ix < 2; ++ix) {
      if (vy[iy] && vx[ix]) {
        float ly_ = fy[iy], hy = 1.0f - ly_;
        float lx_ = fx[ix], hx = 1.0f - lx_;
        acc += hy * (hx * feat[ro0 + xl[ix]] + lx_ * feat[ro0 + xh[ix]]) +
               ly_ * (hx * feat[ro1 + xl[ix]] + lx_ * feat[ro1 + xh[ix]]);
      }
    }
  }
  out[o] = acc * 0.25f;
}

extern "C" void kernel_launch(void* const* d_in, const int* in_sizes, int n_in,
                              void* d_out, int out_size, void* d_ws, size_t ws_size,
                              hipStream_t stream) {
  const float* feat = (const float*)d_in[0];
  const float* rois = (const float*)d_in[1];
  float* out = (float*)d_out;
  int n = out_size;
  size_t need = (size_t)NB * FHW * NC * sizeof(u16);  // 33.55 MB
  if (ws_size >= need) {
    repack_kernel<<<dim3(FHW / 64, NC / 64, NB), 256, 0, stream>>>(feat, (u16*)d_ws);
    gather_kernel<<<dim3(GATHER_BLOCKS), 256, 0, stream>>>((const u16*)d_ws, rois, out);
  } else {
    ROIAlign_direct<<<(n + 255) / 256, 256, 0, stream>>>(feat, rois, out, n);
  }
}

// Round 12
// 55.876 us; speedup vs baseline: 1.3552x; 1.1402x over previous
//
#include <hip/hip_runtime.h>

// ROIAlign, MI355X. feat (4,256,128,128) f32, rois (1024,5) f32,
// out (1024,256,7,7) f32. scale=0.25, sampling=2.
// FINAL (round-8 structure, best measured: 55.4 us total).
// Pipeline: repack NCHW f32 -> NHWC bf16 in d_ws (memory-floor ~14 us);
// gather with 16-lane slot per bin, lane owns 8 channels (uint4 corner
// loads), LDS-staged transposed writeout (coalesced stores). 2048 x
// 256-thread blocks (25.3KB LDS).
// Levers tested and rejected: XCD-sorted locality (r9, -3us), 16-load ILP
// hoist (r10, VGPR 180 -> -21us), persistent balanced blocks (r11, -7us).
// Gather is request-path/latency bound: ~1.34M unique 64B lines, L2-miss ->
// L3, with VALU/HBM/LDS all far from ceiling.

typedef unsigned short u16;
typedef unsigned int u32;

#define FW 128
#define FHW 16384
#define NC 256
#define NB 4
#define HALF_C 128
#define OUT_PER_HALF 6272   // HALF_C * 49
#define TILE_P 129          // odd row stride -> conflict-free transposed reads

static __device__ __forceinline__ float bfhi(u32 v) {
  return __uint_as_float(v & 0xFFFF0000u);
}
static __device__ __forceinline__ float bflo(u32 v) {
  return __uint_as_float(v << 16);
}

// ---- Kernel 1: transpose [B][C][HW] f32 -> [B][HW][C] bf16 (proven) ----
__global__ __launch_bounds__(256) void repack_kernel(const float* __restrict__ feat,
                                                     u16* __restrict__ ws) {
  __shared__ u16 tile[64][66];
  int hw0 = blockIdx.x * 64;
  int c0  = blockIdx.y * 64;
  int b   = blockIdx.z;
  const float* src = feat + (size_t)b * NC * FHW;
  int t   = threadIdx.x;
  int lhw = t & 63;
  int lc  = t >> 6;
#pragma unroll
  for (int i = 0; i < 16; ++i) {
    int c = lc + i * 4;
    float v = src[(size_t)(c0 + c) * FHW + hw0 + lhw];
    u32 u = __float_as_uint(v);
    u += 0x7FFFu + ((u >> 16) & 1u);  // RNE f32->bf16
    tile[lhw][c] = (u16)(u >> 16);
  }
  __syncthreads();
  u16* dst = ws + (size_t)b * FHW * NC;
  int c2 = (t & 31) * 2;
  int r0 = t >> 5;
#pragma unroll
  for (int i = 0; i < 8; ++i) {
    int r = r0 + i * 8;
    u32 val = *(const u32*)&tile[r][c2];
    *(u32*)&dst[(size_t)(hw0 + r) * NC + c0 + c2] = val;
  }
}

// ---- Kernel 2: gather. grid 2*K (1D), block 256 (16 slots x 16 lanes) ----
// bid -> (k = bid>>1, half = bid&1). Slot t>>4 owns bins: slot 0 -> s 0..3,
// slot j>0 -> s 3j+1..3j+3 (covers 0..48 exactly once). Lane t&15 owns
// channels half*128 + 8*(t&15) .. +7 (uint4 = 8 bf16 per corner load).
// Results staged in LDS tile[s][c_local], then written fully coalesced.
__global__ __launch_bounds__(256) void gather_kernel(const u16* __restrict__ ws,
                                                     const float* __restrict__ rois,
                                                     float* __restrict__ out) {
  __shared__ float tile[49][TILE_P];  // 25.3 KB
  int bid    = blockIdx.x;
  int k      = bid >> 1;
  int half   = bid & 1;
  int t      = threadIdx.x;
  int slot   = t >> 4;    // 0..15
  int lane16 = t & 15;
  int cl     = lane16 * 8;              // channel offset within half

  int   b  = (int)rois[k * 5 + 0];
  float x1 = rois[k * 5 + 1] * 0.25f;
  float y1 = rois[k * 5 + 2] * 0.25f;
  float x2 = rois[k * 5 + 3] * 0.25f;
  float y2 = rois[k * 5 + 4] * 0.25f;
  float bw = fmaxf(x2 - x1, 1.0f) * (1.0f / 7.0f);
  float bh = fmaxf(y2 - y1, 1.0f) * (1.0f / 7.0f);

  const u16* plane = ws + (size_t)b * FHW * NC + half * HALF_C + cl;
  const int s0 = slot ? 3 * slot + 1 : 0;
  const int nb = slot ? 3 : 4;

  float acc[4][8];
#pragma unroll
  for (int i = 0; i < 4; ++i)
#pragma unroll
    for (int ch = 0; ch < 8; ++ch) acc[i][ch] = 0.0f;

#pragma unroll
  for (int i = 0; i < 4; ++i) {
    if (i < nb) {  // uniform within 16-lane slot; acc indices stay static
      int s  = s0 + i;
      int ph = s / 7, pw = s - ph * 7;

      int xl[2], xh[2]; float fx[2]; bool vx[2];
#pragma unroll
      for (int ix = 0; ix < 2; ++ix) {
        float xx = x1 + bw * ((float)pw + (ix ? 0.75f : 0.25f));
        vx[ix] = (xx >= -1.0f) && (xx <= 128.0f);
        float xc = fmaxf(xx, 0.0f);
        int l = min((int)xc, 127);
        xl[ix] = l; xh[ix] = min(l + 1, 127); fx[ix] = xc - (float)l;
      }
      int yl[2], yh[2]; float fy[2]; bool vy[2];
#pragma unroll
      for (int iy = 0; iy < 2; ++iy) {
        float yy = y1 + bh * ((float)ph + (iy ? 0.75f : 0.25f));
        vy[iy] = (yy >= -1.0f) && (yy <= 128.0f);
        float yc = fmaxf(yy, 0.0f);
        int l = min((int)yc, 127);
        yl[iy] = l; yh[iy] = min(l + 1, 127); fy[iy] = yc - (float)l;
      }

#pragma unroll
      for (int iy = 0; iy < 2; ++iy) {
#pragma unroll
        for (int ix = 0; ix < 2; ++ix) {
          if (vy[iy] && vx[ix]) {
            float ly_ = fy[iy], hy = 1.0f - ly_;
            float lx_ = fx[ix], hx = 1.0f - lx_;
            float w00 = hy * hx, w01 = hy * lx_, w10 = ly_ * hx, w11 = ly_ * lx_;
            const uint4 v00 = *(const uint4*)(plane + (yl[iy] * FW + xl[ix]) * NC);
            const uint4 v01 = *(const uint4*)(plane + (yl[iy] * FW + xh[ix]) * NC);
            const uint4 v10 = *(const uint4*)(plane + (yh[iy] * FW + xl[ix]) * NC);
            const uint4 v11 = *(const uint4*)(plane + (yh[iy] * FW + xh[ix]) * NC);
            acc[i][0] += w00 * bflo(v00.x) + w01 * bflo(v01.x) + w10 * bflo(v10.x) + w11 * bflo(v11.x);
            acc[i][1] += w00 * bfhi(v00.x) + w01 * bfhi(v01.x) + w10 * bfhi(v10.x) + w11 * bfhi(v11.x);
            acc[i][2] += w00 * bflo(v00.y) + w01 * bflo(v01.y) + w10 * bflo(v10.y) + w11 * bflo(v11.y);
            acc[i][3] += w00 * bfhi(v00.y) + w01 * bfhi(v01.y) + w10 * bfhi(v10.y) + w11 * bfhi(v11.y);
            acc[i][4] += w00 * bflo(v00.z) + w01 * bflo(v01.z) + w10 * bflo(v10.z) + w11 * bflo(v11.z);
            acc[i][5] += w00 * bfhi(v00.z) + w01 * bfhi(v01.z) + w10 * bfhi(v10.z) + w11 * bfhi(v11.z);
            acc[i][6] += w00 * bflo(v00.w) + w01 * bflo(v01.w) + w10 * bflo(v10.w) + w11 * bflo(v11.w);
            acc[i][7] += w00 * bfhi(v00.w) + w01 * bfhi(v01.w) + w10 * bfhi(v10.w) + w11 * bfhi(v11.w);
          }
        }
      }
    }
  }

  // Stage: tile[s][c_local]. Slots cover s=0..48 once; lanes cover
  // c_local=0..127 once -> every cell read below written exactly once.
#pragma unroll
  for (int i = 0; i < 4; ++i) {
    if (i < nb) {
      int s = s0 + i;
#pragma unroll
      for (int ch = 0; ch < 8; ++ch) tile[s][cl + ch] = acc[i][ch] * 0.25f;
    }
  }
  __syncthreads();

  // Coalesced writeout: flat f = c_local*49 + s, consecutive lanes ->
  // consecutive addresses (full-line L2 writebacks).
  float* o = out + (size_t)k * (NC * 49) + half * OUT_PER_HALF;
#pragma unroll
  for (int i = 0; i < 25; ++i) {
    int f = t + i * 256;
    if (f < OUT_PER_HALF) {
      int c = f / 49;  // compiler magic-mul
      int s = f - c * 49;
      o[f] = tile[s][c];
    }
  }
}

// ---- Fallback: direct NCHW kernel (round-2 proven) ----
__global__ __launch_bounds__(256) void ROIAlign_direct(const float* __restrict__ feat,
                                                       const float* __restrict__ rois,
                                                       float* __restrict__ out, int n) {
  int o = blockIdx.x * 256 + threadIdx.x;
  if (o >= n) return;
  int pw = o % 7;
  int t1 = o / 7;
  int ph = t1 % 7;
  int t2 = t1 / 7;
  int c = t2 & 255;
  int k = t2 >> 8;

  int rb = k * 5;
  int b = (int)rois[rb + 0];
  float x1 = rois[rb + 1] * 0.25f, y1 = rois[rb + 2] * 0.25f;
  float x2 = rois[rb + 3] * 0.25f, y2 = rois[rb + 4] * 0.25f;
  float bw = fmaxf(x2 - x1, 1.0f) / 7.0f;
  float bh = fmaxf(y2 - y1, 1.0f) / 7.0f;

  int xl[2], xh[2]; float fx[2]; bool vx[2];
#pragma unroll
  for (int ix = 0; ix < 2; ++ix) {
    float xx = x1 + bw * ((float)pw + (ix ? 0.75f : 0.25f));
    vx[ix] = (xx >= -1.0f) && (xx <= 128.0f);
    float xc = fmaxf(xx, 0.0f);
    int l = min((int)xc, 127);
    xl[ix] = l; xh[ix] = min(l + 1, 127); fx[ix] = xc - (float)l;
  }
  int yl[2], yh[2]; float fy[2]; bool vy[2];
#pragma unroll
  for (int iy = 0; iy < 2; ++iy) {
    float yy = y1 + bh * ((float)ph + (iy ? 0.75f : 0.25f));
    vy[iy] = (yy >= -1.0f) && (yy <= 128.0f);
    float yc = fmaxf(yy, 0.0f);
    int l = min((int)yc, 127);
    yl[iy] = l; yh[iy] = min(l + 1, 127); fy[iy] = yc - (float)l;
  }
  const int plane = (b * 256 + c) << 14;
  float acc = 0.0f;
#pragma unroll
  for (int iy = 0; iy < 2; ++iy) {
    int ro0 = plane + (yl[iy] << 7);
    int ro1 = plane + (yh[iy] << 7);
#pragma unroll
    for (int ix = 0; ix < 2; ++ix) {
      if (vy[iy] && vx[ix]) {
        float ly_ = fy[iy], hy = 1.0f - ly_;
        float lx_ = fx[ix], hx = 1.0f - lx_;
        acc += hy * (hx * feat[ro0 + xl[ix]] + lx_ * feat[ro0 + xh[ix]]) +
               ly_ * (hx * feat[ro1 + xl[ix]] + lx_ * feat[ro1 + xh[ix]]);
      }
    }
  }
  out[o] = acc * 0.25f;
}

extern "C" void kernel_launch(void* const* d_in, const int* in_sizes, int n_in,
                              void* d_out, int out_size, void* d_ws, size_t ws_size,
                              hipStream_t stream) {
  const float* feat = (const float*)d_in[0];
  const float* rois = (const float*)d_in[1];
  float* out = (float*)d_out;
  int K = out_size / (NC * 49);
  size_t need = (size_t)NB * FHW * NC * sizeof(u16);  // 33.55 MB
  if (ws_size >= need) {
    repack_kernel<<<dim3(FHW / 64, NC / 64, NB), 256, 0, stream>>>(feat, (u16*)d_ws);
    gather_kernel<<<dim3(2 * K), 256, 0, stream>>>((const u16*)d_ws, rois, out);
  } else {
    int n = out_size;
    ROIAlign_direct<<<(n + 255) / 256, 256, 0, stream>>>(feat, rois, out, n);
  }
}